// Round 14
// baseline (93.183 us; speedup 1.0000x reference)
//
#include <hip/hip_runtime.h>

#define NEXP 8
#define NFB 2048        // fill blocks (dispatched FIRST)
#define NPB 512         // probs blocks (16 tokens each: 8 waves x 2)
#define NRK 256         // rank blocks (32 pairs x 8 slices)
#define NTHR 512

typedef unsigned long long u64;
typedef unsigned int u32;
typedef float f32x4 __attribute__((ext_vector_type(4)));

#define LOAD_AGT(p)     __hip_atomic_load((p), __ATOMIC_RELAXED, __HIP_MEMORY_SCOPE_AGENT)
#define STORE_AGT(p,v)  __hip_atomic_store((p), (v), __ATOMIC_RELAXED, __HIP_MEMORY_SCOPE_AGENT)

// flags (ints, 64B-padded): pflag[g] at [g*16], rkflag[g] at [(4+g)*16]
union __align__(16) Smem {
    struct { float wl[NEXP * 1024]; double zred[8]; } a;      // probs
    struct { u64 keys[2048]; int part[NTHR]; } b;             // rank
    struct { int avail[2048]; int cnt[32]; int cnt2[32]; } c; // assign
};

__global__ __launch_bounds__(NTHR) void moe_fused_kernel(
    const float* __restrict__ x,      // [GT, 1024]
    const float* __restrict__ w,      // [8, 1024]
    const float* __restrict__ bias,   // [8]
    float* __restrict__ out,
    float* probsT,                    // [E][GT]   (sc1 channel)
    u64* skey,                        // [E*G][T]  (sc1 channel)
    double* zpart,                    // [NPB]     (sc1 channel)
    u64* cbufg,                       // [G][E][cap] -> read by k2
    double* zsc,                      // [1]        -> read by k2
    int* flags,
    long long nout4, long long GT, int T, int G, int cap)
{
    __shared__ Smem sm;
    const int b = blockIdx.x;
    const int tid = threadIdx.x;
    const int lane = tid & 63;
    const int wv = tid >> 6;

    if (b < NFB) {
        // ============ fill: pure streaming, dispatched first ============
        if (b == 0 && tid < 128) STORE_AGT(&flags[tid], 0);   // sc1: no dirty-L2 line
        const long long stride = (long long)NFB * NTHR;
        const f32x4 z = {0.f, 0.f, 0.f, 0.f};
        f32x4* o4 = reinterpret_cast<f32x4*>(out);
        for (long long k = (long long)b * NTHR + tid; k < nout4; k += stride)
            __builtin_nontemporal_store(z, o4 + k);
        return;
    }

    if (b < NFB + NPB) {
        // ============ probs: 16 tokens (8 waves x 2, sequential) ============
        const int pb = b - NFB;
        for (int i = tid; i < NEXP * 1024 / 4; i += NTHR)
            reinterpret_cast<float4*>(sm.a.wl)[i] = reinterpret_cast<const float4*>(w)[i];
        __syncthreads();

        double zacc = 0.0;
#pragma unroll
        for (int s = 0; s < 2; ++s) {
            const long long t = (long long)pb * 16 + wv * 2 + s;
            const float* xr = x + t * 1024;
            float acc[NEXP];
#pragma unroll
            for (int e = 0; e < NEXP; ++e) acc[e] = 0.f;
#pragma unroll
            for (int c = 0; c < 4; ++c) {
                const float4 xv = reinterpret_cast<const float4*>(xr)[c * 64 + lane];
#pragma unroll
                for (int e = 0; e < NEXP; ++e) {
                    const float4 wv4 = reinterpret_cast<const float4*>(sm.a.wl + e * 1024)[c * 64 + lane];
                    acc[e] = fmaf(xv.x, wv4.x, acc[e]);
                    acc[e] = fmaf(xv.y, wv4.y, acc[e]);
                    acc[e] = fmaf(xv.z, wv4.z, acc[e]);
                    acc[e] = fmaf(xv.w, wv4.w, acc[e]);
                }
            }
#pragma unroll
            for (int e = 0; e < NEXP; ++e) {
#pragma unroll
                for (int off = 32; off; off >>= 1) acc[e] += __shfl_xor(acc[e], off, 64);
            }
            if (lane == 0) {
                double l[NEXP]; double mx = -1e300;
#pragma unroll
                for (int e = 0; e < NEXP; ++e) { l[e] = (double)acc[e] + (double)bias[e]; mx = fmax(mx, l[e]); }
                double ex[NEXP]; double ssum = 0.0;
#pragma unroll
                for (int e = 0; e < NEXP; ++e) { ex[e] = exp(l[e] - mx); ssum += ex[e]; }
                const double inv = 1.0 / ssum;
#pragma unroll
                for (int e = 0; e < NEXP; ++e)
                    STORE_AGT(&probsT[(long long)e * GT + t], (float)(ex[e] * inv));
                const double lse = mx + log(ssum);
                zacc += lse * lse;
            }
        }
        if (lane == 0) sm.a.zred[wv] = zacc;
        __syncthreads();   // compiler emits vmcnt(0) before barrier: probsT drained
        if (tid == 0) {
            double ssum = 0.0;
#pragma unroll
            for (int i = 0; i < 8; ++i) ssum += sm.a.zred[i];
            STORE_AGT(&zpart[pb], ssum);
            asm volatile("s_waitcnt vmcnt(0)" ::: "memory");
            atomicAdd(&flags[(pb >> 7) * 16], 1);   // pflag[g], g = pb/128
        }
        return;
    }

    if (b < NFB + NPB + NRK) {
        // ============ rank: pair = e*G+g, slice of 256 tokens ============
        const int b2 = b - NFB - NPB;
        const int pair = b2 >> 3;
        const int sub  = b2 & 7;
        const int e = pair / G;
        const int g = pair - e * G;
        if (tid == 0) {
            while (LOAD_AGT(&flags[g * 16]) < NPB / 4)
                __builtin_amdgcn_s_sleep(64);       // slow poll: ~1.7 us period
        }
        __syncthreads();

        float* p = probsT + (long long)e * GT + (long long)g * T;
        for (int j = tid; j < 2048; j += NTHR)
            sm.b.keys[j] = ((u64)__float_as_uint(LOAD_AGT(&p[j])) << 32) | (u32)(~(u32)j);
        __syncthreads();
        const int slot = tid & 255;
        const int q = tid >> 8;                     // compare-range half 0..1
        const u64 kt = sm.b.keys[sub * 256 + slot];
        const ulonglong2* k2p = reinterpret_cast<const ulonglong2*>(sm.b.keys) + q * 512;
        int r = 0;
#pragma unroll 8
        for (int j = 0; j < 512; ++j) {
            const ulonglong2 v = k2p[j];
            r += (v.x > kt); r += (v.y > kt);
        }
        sm.b.part[tid] = r;
        __syncthreads();
        if (tid < 256) {
            const int rank = sm.b.part[tid] + sm.b.part[tid + 256];
            STORE_AGT(&skey[(long long)pair * T + rank], sm.b.keys[sub * 256 + tid]);
        }
        asm volatile("s_waitcnt vmcnt(0)" ::: "memory");
        __syncthreads();
        if (tid == 0) atomicAdd(&flags[(4 + g) * 16], 1);
        return;
    }

    // ============ assign for group g: compute -> cbufg (no output writes) ====
    const int g = b - NFB - NPB - NRK;
    if (tid == 0) {
        while (LOAD_AGT(&flags[(4 + g) * 16]) < NRK / 4)
            __builtin_amdgcn_s_sleep(64);
        if (g == 0) {
            for (int gg = 0; gg < 4; ++gg)
                while (LOAD_AGT(&flags[gg * 16]) < NPB / 4)
                    __builtin_amdgcn_s_sleep(64);
        }
    }
    __syncthreads();

    for (int j = tid; j < 2048; j += NTHR) sm.c.avail[j] = 1;
    const u64 lmask = (lane == 0) ? 0ull : ((~0ull) >> (64 - lane));
    u64* cb = cbufg + (long long)g * NEXP * cap;

    for (int e = 0; e < NEXP; ++e) {
        const long long kb = (long long)(e * G + g) * T;
        u64 k[4];
#pragma unroll
        for (int j = 0; j < 4; ++j) k[j] = LOAD_AGT(&skey[kb + tid + j * NTHR]);
        __syncthreads();                         // B_top: prior avail updates visible
        u32 idx[4]; int f[4]; u64 m[4];
#pragma unroll
        for (int j = 0; j < 4; ++j) {
            idx[j] = ~(u32)k[j];
            f[j] = sm.c.avail[idx[j]];
            m[j] = __ballot(f[j]);
            if (lane == 0) sm.c.cnt[wv + 8 * j] = __popcll(m[j]);
        }
        __syncthreads();                         // B1
        int vi = (lane < 32) ? sm.c.cnt[lane] : 0;
#pragma unroll
        for (int o = 1; o < 32; o <<= 1) { const int t2 = __shfl_up(vi, o, 64); if (lane >= o) vi += t2; }
        const int S = __shfl(vi, 31, 64);
        bool sel[4];
#pragma unroll
        for (int j = 0; j < 4; ++j) {
            const int seg = wv + 8 * j;
            const int off = seg ? __shfl(vi, seg - 1, 64) : 0;
            const int pre = off + __popcll(m[j] & lmask);
            sel[j] = f[j] && (pre < cap);
            if (sel[j]) cb[e * cap + pre] = ((k[j] >> 32) << 32) | (u64)idx[j];
        }
        if (S < cap) {
            // zero-gate fill: smallest-index unavailable tokens (val = 0)
            int u[4]; u64 n[4];
#pragma unroll
            for (int j = 0; j < 4; ++j) {
                u[j] = 1 - sm.c.avail[tid + j * NTHR];
                n[j] = __ballot(u[j]);
                if (lane == 0) sm.c.cnt2[wv + 8 * j] = __popcll(n[j]);
            }
            __syncthreads();                     // B2: cnt2 visible; u-reads done
            int vj = (lane < 32) ? sm.c.cnt2[lane] : 0;
#pragma unroll
            for (int o = 1; o < 32; o <<= 1) { const int t2 = __shfl_up(vj, o, 64); if (lane >= o) vj += t2; }
            const int nfill = cap - S;
#pragma unroll
            for (int j = 0; j < 4; ++j) {
                const int seg = wv + 8 * j;
                const int qoff = seg ? __shfl(vj, seg - 1, 64) : 0;
                const int qj = qoff + __popcll(n[j] & lmask);
                if (u[j] && qj < nfill) cb[e * cap + S + qj] = (u64)(u32)(tid + j * NTHR);
            }
        }
#pragma unroll
        for (int j = 0; j < 4; ++j) if (sel[j]) sm.c.avail[idx[j]] = 0;
    }

    if (g == 0) {
        __syncthreads();
        if (tid < 64) {
            double s = 0.0;
            for (int i = tid; i < NPB; i += 64) s += LOAD_AGT(&zpart[i]);
#pragma unroll
            for (int o = 32; o; o >>= 1) s += __shfl_xor(s, o, 64);
            if (tid == 0) zsc[0] = s;
        }
    }
}

// ---------------- kernel 2: scatter compact results over k1's zeros ----------
// kernel boundary = full flush: no WAW hazard with k1's fill.
__global__ __launch_bounds__(NTHR) void scatter_kernel(
    const u64* __restrict__ cbufg,   // [G][E][cap]
    const double* __restrict__ zsc,
    float* __restrict__ out,
    long long nout4, int out_size,
    int T, int G, int cap, long long GT)
{
    const int g = blockIdx.x;
    const int tid = threadIdx.x;
    float* dispatch = out;
    float* combine  = out + GT * (long long)NEXP * cap;
    const long long gbase = (long long)g * T;
    const u64* cb = cbufg + (long long)g * NEXP * cap;

#pragma unroll
    for (int e = 0; e < NEXP; ++e) {
        for (int c = tid; c < cap; c += NTHR) {
            const u64 en = cb[e * cap + c];
            const u32 idx = (u32)en;
            const float val = __uint_as_float((u32)(en >> 32));
            const long long o_ = ((gbase + idx) * NEXP + e) * (long long)cap + c;
            dispatch[o_] = 1.0f;
            combine[o_]  = val;
        }
    }
    if (g == 0 && tid == 0) {
        float* sc = out + 2 * GT * (long long)NEXP * cap;
        for (long long j = nout4 * 4; j < (long long)out_size - 3; ++j) out[j] = 0.f;
        sc[0] = 0.0f;
        sc[1] = (float)(zsc[0] / (double)GT);
        sc[2] = 0.0f;
    }
}

extern "C" void kernel_launch(void* const* d_in, const int* in_sizes, int n_in,
                              void* d_out, int out_size, void* d_ws, size_t ws_size,
                              hipStream_t stream) {
    (void)n_in; (void)ws_size;
    const float* x    = (const float*)d_in[0];
    const float* w    = (const float*)d_in[1];
    const float* bias = (const float*)d_in[2];

    const int E = in_sizes[2];                        // 8
    const int D = in_sizes[1] / E;                    // 1024
    const long long GT = (long long)in_sizes[0] / D;  // 8192
    const int T = 2048;
    const int G = (int)(GT / T);                      // 4
    const int cap = (int)(((long long)out_size - 3) / (2 * GT * E));
    const long long nout4 = ((long long)out_size - 3) >> 2;

    int*    flags  = (int*)d_ws;                                   // [0,512)
    double* zsc    = (double*)((char*)d_ws + 1024);                // 8 B
    double* zpart  = (double*)((char*)d_ws + 4096);                // NPB*8
    float*  probsT = (float*)((char*)d_ws + 16384);                // E*GT*4
    u64*    skey   = (u64*)((char*)d_ws + 16384 + (size_t)E * GT * sizeof(float));
    u64*    cbufg  = (u64*)((char*)d_ws + 16384 + (size_t)E * GT * sizeof(float)
                                        + (size_t)E * G * T * sizeof(u64));

    moe_fused_kernel<<<NFB + NPB + NRK + G, NTHR, 0, stream>>>(
        x, w, bias, (float*)d_out, probsT, skey, zpart, cbufg, zsc, flags,
        nout4, GT, T, G, cap);

    scatter_kernel<<<G, NTHR, 0, stream>>>(
        cbufg, zsc, (float*)d_out, nout4, out_size, T, G, cap, GT);
}